// Round 21
// baseline (132.118 us; speedup 1.0000x reference)
//
#include <hip/hip_runtime.h>

// GATConv: N=50000, NIN=128, H=4, C=16 (HC=64), E=800000 (+N self-loops,
// synthesized inside k_gat). Slot-table aggregation (no CSR), packed edges
// (s|d<<16, fused into k_xw). k_gat is straight-line depth-2: deg<=CAP=32
// means exactly two 16-edge blocks, processed as independent register
// streams (32 gathers in flight; r20's serial blocks were the latency chain).
#define NN 50000
#define NIN 128
#define NH 4
#define NC 16
#define HC 64
#define NE 800000
#define NEG_SLOPE 0.2f
#define RPB 16                       // rows per block in k_xw (LDS 40KB -> 4 blk/CU)
#define NPART 8                      // dst partitions (== XCD count)
#define SCHUNK 256                   // blocks per partition in k_scatter
#define DPP (NN / NPART)             // 6250 dst per partition
#define GPB 1563                     // gat blocks per partition = ceil(6250/4)
#define CAP 32                       // slots per destination
#define OFCAP 8192                   // overflow list capacity (safety margin)

__device__ __forceinline__ ushort f2bf(float v) {  // RNE f32->bf16
  unsigned u = __float_as_uint(v);
  return (ushort)((u + 0x7FFFu + ((u >> 16) & 1u)) >> 16);
}
__device__ __forceinline__ float bf2f(ushort b) {
  return __uint_as_float((unsigned)b << 16);
}
__device__ __forceinline__ float lrelu_exp(float e) {
  e = e > 0.f ? e : NEG_SLOPE * e;
  return __expf(fminf(e, 60.f));  // no max-shift needed: |e|<~12 on this data
}

// xw(bf16) = x @ W (Ws+xs in LDS, 16 rows/block, 4 rows/thread), att dots
// fused. Also: packs edge gi (3125*256 == NE exactly; coalesced, fire-and-
// forget, overlaps the matmul) and zeroes cnt[]/ofcnt.
__global__ __launch_bounds__(256, 4) void k_xw(
    const float* __restrict__ x, const float* __restrict__ W,
    const float* __restrict__ att_src, const float* __restrict__ att_dst,
    ushort* __restrict__ xwb, float* __restrict__ a_src, float* __restrict__ a_dst,
    int* __restrict__ cnt, int* __restrict__ ofcnt,
    const int* __restrict__ ei, unsigned* __restrict__ pk) {
  __shared__ float Ws[NIN][HC];   // 32 KB
  __shared__ float xs[RPB][NIN];  // 8 KB
  int tid = threadIdx.x;
  int gi = blockIdx.x * 256 + tid;  // in [0, NE)
  pk[gi] = (unsigned)ei[gi] | ((unsigned)ei[NE + gi] << 16);
  if (gi < NN) cnt[gi] = 0;
  if (gi == 0) *ofcnt = 0;
  int row0 = blockIdx.x * RPB;  // NN % RPB == 0
  {
    const float4* wsrc = (const float4*)W;
    float4* wdst = (float4*)&Ws[0][0];
    for (int i = tid; i < NIN * HC / 4; i += 256) wdst[i] = wsrc[i];
    const float4* xsrc = (const float4*)(x + (size_t)row0 * NIN);
    float4* xdst = (float4*)&xs[0][0];
    for (int i = tid; i < RPB * (NIN / 4); i += 256) xdst[i] = xsrc[i];
  }
  __syncthreads();
  int j = tid & 63;
  int r4 = (tid >> 6) * 4;  // this wave's 4 rows
  float acc[4] = {0.f, 0.f, 0.f, 0.f};
#pragma unroll 2
  for (int k0 = 0; k0 < NIN; k0 += 4) {
    float w0 = Ws[k0 + 0][j], w1 = Ws[k0 + 1][j];
    float w2 = Ws[k0 + 2][j], w3 = Ws[k0 + 3][j];
#pragma unroll
    for (int r = 0; r < 4; ++r) {
      float4 xv = *(const float4*)&xs[r4 + r][k0];
      acc[r] += xv.x * w0 + xv.y * w1 + xv.z * w2 + xv.w * w3;
    }
  }
  int h = j >> 4, c = j & 15;
  float as = att_src[h * NC + c], ad = att_dst[h * NC + c];
#pragma unroll
  for (int r = 0; r < 4; ++r) {
    int gr = row0 + r4 + r;
    float v = acc[r];
    float ps = v * as, pd = v * ad;
#pragma unroll
    for (int off = 8; off >= 1; off >>= 1) {
      ps += __shfl_xor(ps, off, 64);
      pd += __shfl_xor(pd, off, 64);
    }
    xwb[(size_t)gr * HC + j] = f2bf(v);
    if (c == 0) {
      a_src[gr * NH + h] = ps;
      a_dst[gr * NH + h] = pd;
    }
  }
}

// dst-partitioned slot scatter, true minimum: packed-stream read (L3-resident
// on re-read), cursor atomic, one 2B store. No gathers, no exp, no score.
// XCD-affine: block b serves partition b&7 so slot regions stay L2-local.
__global__ __launch_bounds__(256) void k_scatter(
    const unsigned* __restrict__ pk, int* __restrict__ cnt,
    ushort* __restrict__ ss_slot,
    int* __restrict__ ofcnt, unsigned* __restrict__ of) {
  int p = blockIdx.x & (NPART - 1);
  int chunk = blockIdx.x >> 3;  // 0..SCHUNK-1
  int dlo = p * DPP, dhi = dlo + DPP;
  const uint4* p4 = (const uint4*)pk;
  const int ngroups = NE / 4;  // 200000
  for (int g = chunk * 256 + threadIdx.x; g < ngroups; g += SCHUNK * 256) {
    uint4 r4 = p4[g];
#pragma unroll
    for (int c = 0; c < 4; ++c) {
      unsigned r = (c == 0) ? r4.x : (c == 1) ? r4.y : (c == 2) ? r4.z : r4.w;
      int d = (int)(r >> 16);
      if (d >= dlo && d < dhi) {
        int pos = atomicAdd(&cnt[d], 1);
        if (pos < CAP) {
          ss_slot[d * CAP + pos] = (ushort)(r & 0xFFFFu);
        } else {
          int op = atomicAdd(ofcnt, 1);
          if (op < OFCAP) of[op] = r;
        }
      }
    }
  }
}

// one wave per destination node, STRAIGHT-LINE DEPTH-2 (deg<=CAP=32 = two
// 16-edge blocks as independent register streams: s_j0/al0/acc0 and
// s_j1/al1/acc1, interleaved gathers -> 32 loads in flight, split fma chain).
// Alpha recomputed from L2-resident a_src. Overflow replayed at the end.
// XCD-affine mapping. Lane layout head-major: lane j = head(j>>4) x slot(j&15).
__global__ __launch_bounds__(256) void k_gat(
    const int* __restrict__ cnt, const ushort* __restrict__ ss_slot,
    const int* __restrict__ ofcnt, const unsigned* __restrict__ of,
    const float* __restrict__ a_src, const float* __restrict__ a_dst,
    const ushort* __restrict__ xwb, const float* __restrict__ bias,
    float* __restrict__ out) {
  int tid = threadIdx.x;
  int wv = tid >> 6, j = tid & 63;
  int p = blockIdx.x & (NPART - 1);
  int idx = blockIdx.x >> 3;  // 0..GPB-1
  int dd = idx * 4 + wv;
  if (dd >= DPP) return;      // tail block: 2 idle waves
  int d = p * DPP + dd;
  int h = j >> 4, sl = j & 15;
  int base = d * CAP;
  int deg = min(cnt[d], CAP);  // cnt may exceed CAP (overflowed arrivals)

  float adr = a_dst[(size_t)d * NH + h];
  float ws = lrelu_exp(a_src[(size_t)d * NH + h] + adr);  // self score
  float lsum = (sl == 0) ? ws : 0.f;           // per-lane partial denominator
  float acc0 = ws * bf2f(xwb[(size_t)d * HC + j]);  // self contribution
  float acc1 = 0.f;

  int nb0 = min(16, deg);
  int nb1 = deg - 16;  // may be <= 0
  int s_j0 = 0, s_j1 = 0;
  float al0 = 0.f, al1 = 0.f;
  if (sl < nb0) {
    s_j0 = (int)ss_slot[base + sl];
    al0 = lrelu_exp(a_src[(size_t)s_j0 * NH + h] + adr);
  }
  if (sl < nb1) {
    s_j1 = (int)ss_slot[base + 16 + sl];
    al1 = lrelu_exp(a_src[(size_t)s_j1 * NH + h] + adr);
  }
  lsum += al0 + al1;
  if (nb0 == 16 && nb1 == 16) {
#pragma unroll
    for (int k = 0; k < 16; ++k) {
      int s0 = __builtin_amdgcn_readlane(s_j0, k);  // groups replicate
      int s1 = __builtin_amdgcn_readlane(s_j1, k);
      float p0 = __shfl(al0, k, 16);
      float p1 = __shfl(al1, k, 16);
      acc0 += p0 * bf2f(xwb[(size_t)s0 * HC + j]);
      acc1 += p1 * bf2f(xwb[(size_t)s1 * HC + j]);
    }
  } else {
    if (nb0 == 16) {
#pragma unroll
      for (int k = 0; k < 16; ++k) {
        int s0 = __builtin_amdgcn_readlane(s_j0, k);
        float p0 = __shfl(al0, k, 16);
        acc0 += p0 * bf2f(xwb[(size_t)s0 * HC + j]);
      }
    } else {
      for (int k = 0; k < nb0; ++k) {
        int s0 = __shfl(s_j0, k, 16);
        float p0 = __shfl(al0, k, 16);
        acc0 += p0 * bf2f(xwb[(size_t)s0 * HC + j]);
      }
    }
    for (int k = 0; k < nb1; ++k) {
      int s1 = __shfl(s_j1, k, 16);
      float p1 = __shfl(al1, k, 16);
      acc1 += p1 * bf2f(xwb[(size_t)s1 * HC + j]);
    }
  }
  float acc = acc0 + acc1;
  // overflow replay (tiny; all-lane cached reads, match on d, recompute alpha)
  int oc = min(*ofcnt, OFCAP);
  for (int e = 0; e < oc; ++e) {
    unsigned r = of[e];
    if ((int)(r >> 16) == d) {
      int s = (int)(r & 0xFFFFu);
      float al = lrelu_exp(a_src[(size_t)s * NH + h] + adr);
      if (sl == 0) lsum += al;
      acc += al * bf2f(xwb[(size_t)s * HC + j]);
    }
  }
  float L = lsum;
#pragma unroll
  for (int off = 8; off >= 1; off >>= 1) L += __shfl_xor(L, off, 64);
  out[(size_t)d * HC + j] = acc / (L + 1e-16f) + bias[j];
}

extern "C" void kernel_launch(void* const* d_in, const int* in_sizes, int n_in,
                              void* d_out, int out_size, void* d_ws, size_t ws_size,
                              hipStream_t stream) {
  const float* x       = (const float*)d_in[0];
  const int*   ei      = (const int*)d_in[1];
  // d_in[2] = edge_attr: ignored by the reference layer
  const float* W       = (const float*)d_in[3];
  const float* att_src = (const float*)d_in[4];
  const float* att_dst = (const float*)d_in[5];
  const float* bias    = (const float*)d_in[6];
  float* out = (float*)d_out;

  char* p = (char*)d_ws;
  ushort*   xwb     = (ushort*)p;   p += (size_t)NN * HC * 2;    // 6.4 MB
  float*    a_src   = (float*)p;    p += (size_t)NN * NH * 4;    // 0.8 MB
  float*    a_dst   = (float*)p;    p += (size_t)NN * NH * 4;    // 0.8 MB
  int*      cnt     = (int*)p;      p += (size_t)NN * 4;         // 0.2 MB
  int*      ofcnt   = (int*)p;      p += 64;                     // 1 + pad
  ushort*   ss_slot = (ushort*)p;   p += (size_t)NN * CAP * 2;   // 3.2 MB
  unsigned* of      = (unsigned*)p; p += (size_t)OFCAP * 4;      // 32 KB
  unsigned* pk      = (unsigned*)p; p += (size_t)NE * 4;         // 3.2 MB

  k_xw<<<NN / RPB, 256, 0, stream>>>(x, W, att_src, att_dst,
                                     xwb, a_src, a_dst, cnt, ofcnt, ei, pk);
  k_scatter<<<NPART * SCHUNK, 256, 0, stream>>>(pk, cnt, ss_slot, ofcnt, of);
  k_gat<<<NPART * GPB, 256, 0, stream>>>(cnt, ss_slot, ofcnt, of,
                                         a_src, a_dst, xwb, bias, out);
}

// Round 22
// 104.632 us; speedup vs baseline: 1.2627x; 1.2627x over previous
//
#include <hip/hip_runtime.h>

// GATConv: N=50000, NIN=128, H=4, C=16 (HC=64), E=800000 (+N self-loops,
// synthesized inside k_gat). Slot-table aggregation (no CSR), packed edges
// (s|d<<16, fused into k_xw). k_xw now uses MFMA (bf16 in, fp32 acc):
// wave w = head w = cols 16w..16w+15; 4x mfma_f32_16x16x32_bf16 over K=128.
// k_gat/k_scatter are the r20-verified minimal forms (r21 lesson: per-wave
// ILP in k_gat costs VGPR/occupancy and always loses).
#define NN 50000
#define NIN 128
#define NH 4
#define NC 16
#define HC 64
#define NE 800000
#define NEG_SLOPE 0.2f
#define RPB 16                       // rows per block in k_xw
#define NPART 8                      // dst partitions (== XCD count)
#define SCHUNK 256                   // blocks per partition in k_scatter
#define DPP (NN / NPART)             // 6250 dst per partition
#define GPB 1563                     // gat blocks per partition = ceil(6250/4)
#define CAP 32                       // slots per destination
#define OFCAP 8192                   // overflow list capacity (safety margin)

typedef __attribute__((ext_vector_type(8))) __bf16 bf16x8;
typedef __attribute__((ext_vector_type(4))) float f32x4;

__device__ __forceinline__ ushort f2bf(float v) {  // RNE f32->bf16
  unsigned u = __float_as_uint(v);
  return (ushort)((u + 0x7FFFu + ((u >> 16) & 1u)) >> 16);
}
__device__ __forceinline__ float bf2f(ushort b) {
  return __uint_as_float((unsigned)b << 16);
}
__device__ __forceinline__ float lrelu_exp(float e) {
  e = e > 0.f ? e : NEG_SLOPE * e;
  return __expf(fminf(e, 60.f));  // no max-shift needed: |e|<~12 on this data
}

// xw(bf16) = x @ W via MFMA. Block = 16 x-rows; wave w computes the 16x16
// tile for head w (cols 16w..16w+15) with 4 chained mfma_f32_16x16x32_bf16.
// x-tile and W^T staged bf16 in LDS (rows padded +8 to break 256B-stride
// bank conflicts). C/D layout (m89-verified): col=lane&15, row=(lane>>4)*4+q.
// Attention dots reduce over the 16-lane col group. Also packs edge gi
// (3125*256 == NE) and zeroes cnt[]/ofcnt.
__global__ __launch_bounds__(256, 4) void k_xw(
    const float* __restrict__ x, const float* __restrict__ W,
    const float* __restrict__ att_src, const float* __restrict__ att_dst,
    ushort* __restrict__ xwb, float* __restrict__ a_src, float* __restrict__ a_dst,
    int* __restrict__ cnt, int* __restrict__ ofcnt,
    const int* __restrict__ ei, unsigned* __restrict__ pk) {
  __shared__ ushort Wt[HC][NIN + 8];   // W transposed, bf16: 17.4 KB
  __shared__ ushort xs[RPB][NIN + 8];  // x tile, bf16: 4.4 KB
  int tid = threadIdx.x;
  int gi = blockIdx.x * 256 + tid;  // in [0, NE)
  pk[gi] = (unsigned)ei[gi] | ((unsigned)ei[NE + gi] << 16);
  if (gi < NN) cnt[gi] = 0;
  if (gi == 0) *ofcnt = 0;
  int row0 = blockIdx.x * RPB;  // NN % RPB == 0
  // stage W^T (coalesced global read, scattered 2B LDS writes, one-time)
  for (int i = tid; i < NIN * HC; i += 256) {
    int k = i >> 6, c = i & 63;
    Wt[c][k] = f2bf(W[i]);
  }
  // stage x tile: thread t converts 8 consecutive floats -> one b128 store
  {
    int f = tid * 8;  // 256*8 == 16*128
    int r = f >> 7, k = f & 127;
    const float4* xp = (const float4*)(x + (size_t)row0 * NIN + f);
    float4 v0 = xp[0], v1 = xp[1];
    union { bf16x8 v; ushort u[8]; } pkd;
    pkd.u[0] = f2bf(v0.x); pkd.u[1] = f2bf(v0.y);
    pkd.u[2] = f2bf(v0.z); pkd.u[3] = f2bf(v0.w);
    pkd.u[4] = f2bf(v1.x); pkd.u[5] = f2bf(v1.y);
    pkd.u[6] = f2bf(v1.z); pkd.u[7] = f2bf(v1.w);
    *(bf16x8*)&xs[r][k] = pkd.v;
  }
  __syncthreads();
  int l = tid & 63, w = tid >> 6;   // wave w == head w
  int arow = l & 15;                // A row / B col within tile
  int koff = (l >> 4) * 8;          // k sub-offset for A and B fragments
  f32x4 acc = {0.f, 0.f, 0.f, 0.f};
#pragma unroll
  for (int kt = 0; kt < 4; ++kt) {
    bf16x8 av = *(const bf16x8*)&xs[arow][kt * 32 + koff];
    bf16x8 bv = *(const bf16x8*)&Wt[w * 16 + arow][kt * 32 + koff];
    acc = __builtin_amdgcn_mfma_f32_16x16x32_bf16(av, bv, acc, 0, 0, 0);
  }
  // epilogue: lane holds rows {(l>>4)*4+q} x col (l&15) of head w's tile
  int col = l & 15;
  int rgrp = l >> 4;
  float as_ = att_src[w * NC + col], ad_ = att_dst[w * NC + col];
#pragma unroll
  for (int q = 0; q < 4; ++q) {
    int gr = row0 + rgrp * 4 + q;
    float v = acc[q];
    xwb[(size_t)gr * HC + w * 16 + col] = f2bf(v);
    float ps = v * as_, pd = v * ad_;
#pragma unroll
    for (int off = 8; off >= 1; off >>= 1) {
      ps += __shfl_xor(ps, off, 64);
      pd += __shfl_xor(pd, off, 64);
    }
    if (col == 0) {
      a_src[gr * NH + w] = ps;
      a_dst[gr * NH + w] = pd;
    }
  }
}

// dst-partitioned slot scatter, true minimum: packed-stream read (L3-resident
// on re-read), cursor atomic, one 2B store. No gathers, no exp, no score.
// XCD-affine: block b serves partition b&7 so slot regions stay L2-local.
__global__ __launch_bounds__(256) void k_scatter(
    const unsigned* __restrict__ pk, int* __restrict__ cnt,
    ushort* __restrict__ ss_slot,
    int* __restrict__ ofcnt, unsigned* __restrict__ of) {
  int p = blockIdx.x & (NPART - 1);
  int chunk = blockIdx.x >> 3;  // 0..SCHUNK-1
  int dlo = p * DPP, dhi = dlo + DPP;
  const uint4* p4 = (const uint4*)pk;
  const int ngroups = NE / 4;  // 200000
  for (int g = chunk * 256 + threadIdx.x; g < ngroups; g += SCHUNK * 256) {
    uint4 r4 = p4[g];
#pragma unroll
    for (int c = 0; c < 4; ++c) {
      unsigned r = (c == 0) ? r4.x : (c == 1) ? r4.y : (c == 2) ? r4.z : r4.w;
      int d = (int)(r >> 16);
      if (d >= dlo && d < dhi) {
        int pos = atomicAdd(&cnt[d], 1);
        if (pos < CAP) {
          ss_slot[d * CAP + pos] = (ushort)(r & 0xFFFFu);
        } else {
          int op = atomicAdd(ofcnt, 1);
          if (op < OFCAP) of[op] = r;
        }
      }
    }
  }
}

// one wave per destination node, single sweep over the dst's slot run
// (contiguous at d*CAP); alpha recomputed from L2-resident a_src (r20 form —
// minimal VGPR, max occupancy). Overflow replayed at the end. XCD-affine.
// Lane layout head-major: lane j = head (j>>4) x slot (j&15).
__global__ __launch_bounds__(256) void k_gat(
    const int* __restrict__ cnt, const ushort* __restrict__ ss_slot,
    const int* __restrict__ ofcnt, const unsigned* __restrict__ of,
    const float* __restrict__ a_src, const float* __restrict__ a_dst,
    const ushort* __restrict__ xwb, const float* __restrict__ bias,
    float* __restrict__ out) {
  int tid = threadIdx.x;
  int wv = tid >> 6, j = tid & 63;
  int p = blockIdx.x & (NPART - 1);
  int idx = blockIdx.x >> 3;  // 0..GPB-1
  int dd = idx * 4 + wv;
  if (dd >= DPP) return;      // tail block: 2 idle waves
  int d = p * DPP + dd;
  int h = j >> 4, sl = j & 15;
  int base = d * CAP;
  int deg = min(cnt[d], CAP);  // cnt may exceed CAP (overflowed arrivals)

  float adr = a_dst[(size_t)d * NH + h];
  float ws = lrelu_exp(a_src[(size_t)d * NH + h] + adr);  // self score
  float lsum = (sl == 0) ? ws : 0.f;           // per-lane partial denominator
  float acc = ws * bf2f(xwb[(size_t)d * HC + j]);  // self contribution

  for (int i0 = 0; i0 < deg; i0 += 16) {
    int nb = min(16, deg - i0);
    int s_j = 0;
    float al = 0.f;
    if (sl < nb) {
      s_j = (int)ss_slot[base + i0 + sl];                  // coalesced 2B
      al = lrelu_exp(a_src[(size_t)s_j * NH + h] + adr);   // L2-resident gather
    }
    lsum += al;
    if (nb == 16) {
#pragma unroll
      for (int k = 0; k < 16; ++k) {
        int s = __builtin_amdgcn_readlane(s_j, k);  // lane k holds slot k
        float alpha = __shfl(al, k, 16);
        acc += alpha * bf2f(xwb[(size_t)s * HC + j]);
      }
    } else {
      for (int k = 0; k < nb; ++k) {
        int s = __shfl(s_j, k, 16);
        float alpha = __shfl(al, k, 16);
        acc += alpha * bf2f(xwb[(size_t)s * HC + j]);
      }
    }
  }
  // overflow replay (tiny; all-lane cached reads, match on d, recompute alpha)
  int oc = min(*ofcnt, OFCAP);
  for (int e = 0; e < oc; ++e) {
    unsigned r = of[e];
    if ((int)(r >> 16) == d) {
      int s = (int)(r & 0xFFFFu);
      float al = lrelu_exp(a_src[(size_t)s * NH + h] + adr);
      if (sl == 0) lsum += al;
      acc += al * bf2f(xwb[(size_t)s * HC + j]);
    }
  }
  float L = lsum;
#pragma unroll
  for (int off = 8; off >= 1; off >>= 1) L += __shfl_xor(L, off, 64);
  out[(size_t)d * HC + j] = acc / (L + 1e-16f) + bias[j];
}

extern "C" void kernel_launch(void* const* d_in, const int* in_sizes, int n_in,
                              void* d_out, int out_size, void* d_ws, size_t ws_size,
                              hipStream_t stream) {
  const float* x       = (const float*)d_in[0];
  const int*   ei      = (const int*)d_in[1];
  // d_in[2] = edge_attr: ignored by the reference layer
  const float* W       = (const float*)d_in[3];
  const float* att_src = (const float*)d_in[4];
  const float* att_dst = (const float*)d_in[5];
  const float* bias    = (const float*)d_in[6];
  float* out = (float*)d_out;

  char* p = (char*)d_ws;
  ushort*   xwb     = (ushort*)p;   p += (size_t)NN * HC * 2;    // 6.4 MB
  float*    a_src   = (float*)p;    p += (size_t)NN * NH * 4;    // 0.8 MB
  float*    a_dst   = (float*)p;    p += (size_t)NN * NH * 4;    // 0.8 MB
  int*      cnt     = (int*)p;      p += (size_t)NN * 4;         // 0.2 MB
  int*      ofcnt   = (int*)p;      p += 64;                     // 1 + pad
  ushort*   ss_slot = (ushort*)p;   p += (size_t)NN * CAP * 2;   // 3.2 MB
  unsigned* of      = (unsigned*)p; p += (size_t)OFCAP * 4;      // 32 KB
  unsigned* pk      = (unsigned*)p; p += (size_t)NE * 4;         // 3.2 MB

  k_xw<<<NN / RPB, 256, 0, stream>>>(x, W, att_src, att_dst,
                                     xwb, a_src, a_dst, cnt, ofcnt, ei, pk);
  k_scatter<<<NPART * SCHUNK, 256, 0, stream>>>(pk, cnt, ss_slot, ofcnt, of);
  k_gat<<<NPART * GPB, 256, 0, stream>>>(cnt, ss_slot, ofcnt, of,
                                         a_src, a_dst, xwb, bias, out);
}